// Round 1
// baseline (74.801 us; speedup 1.0000x reference)
//
#include <hip/hip_runtime.h>

// Tropical (max-plus) matmul: out[n,m] = max_k(|x[n,k]| + |w[m,k]|)
// N=1024, K=256, M=1024, fp32 in/out.
//
// Design (round 1):
//  - 64x64 output tile per block -> 256 blocks = 1 block/CU on MI355X.
//  - 256 threads (16x16), each computes a 4x4 register tile.
//  - K chunked by 64; chunk staged to LDS in k-pair-major layout
//    [kk][n]{k0,k1} so the inner loop reads 4 n-values x k-pair with one
//    ds_read_b128 per side-half (2 per side).
//  - abs() applied once at staging time (amortized over reuse).
//  - Inner combine written as <2 x float> add + fmax chain so LLVM emits
//    v_pk_add_f32 + v_max3_f32: 1 VALU inst per k-step per output.
//  - Next chunk's global loads prefetched into registers during compute.

typedef float v2f __attribute__((ext_vector_type(2)));
typedef float v4f __attribute__((ext_vector_type(4)));

constexpr int TILE = 64;     // output tile edge
constexpr int KB   = 64;     // k-chunk
constexpr int KKP  = KB / 2; // k-pairs per chunk = 32
constexpr int PITCH = TILE + 2; // float2 pitch per kk row: 64 data + 2 pad = 528 B (16B-aligned)

static __device__ inline v2f mk2(float a, float b) { v2f r; r.x = a; r.y = b; return r; }

__global__ void __launch_bounds__(256)
tropical_kernel(const float* __restrict__ xg, const float* __restrict__ wg,
                float* __restrict__ outg)
{
    constexpr int K = 256;
    constexpr int M = 1024;

    __shared__ __align__(16) v2f xs[KKP * PITCH];
    __shared__ __align__(16) v2f ws[KKP * PITCH];

    const int tid = threadIdx.x;
    const int tx = tid & 15;   // m-side thread coord
    const int ty = tid >> 4;   // n-side thread coord
    const int bn = (int)(blockIdx.x >> 4) * TILE;
    const int bm = (int)(blockIdx.x & 15) * TILE;

    // Staging: thread loads rows (ty + 16*i), k-cols [4*tx, 4*tx+4) of the chunk.
    const float* xbase = xg + (bn + ty) * K + 4 * tx;
    const float* wbase = wg + (bm + ty) * K + 4 * tx;

    // Prefetch chunk 0 into registers.
    v4f xr[4], wr[4];
#pragma unroll
    for (int i = 0; i < 4; ++i) {
        xr[i] = *(const v4f*)(xbase + (16 * i) * K);
        wr[i] = *(const v4f*)(wbase + (16 * i) * K);
    }

    // All sums are >= 0 (abs + abs), so 0 is a safe identity for max.
    float acc[4][4];
#pragma unroll
    for (int i = 0; i < 4; ++i)
#pragma unroll
        for (int j = 0; j < 4; ++j) acc[i][j] = 0.0f;

    for (int chunk = 0; chunk < K / KB; ++chunk) {
        __syncthreads();  // previous chunk's LDS reads done
#pragma unroll
        for (int i = 0; i < 4; ++i) {
            v4f fx = xr[i], fw = wr[i];
            int n = ty + 16 * i;
            xs[(2 * tx)     * PITCH + n] = mk2(fabsf(fx.x), fabsf(fx.y));
            xs[(2 * tx + 1) * PITCH + n] = mk2(fabsf(fx.z), fabsf(fx.w));
            ws[(2 * tx)     * PITCH + n] = mk2(fabsf(fw.x), fabsf(fw.y));
            ws[(2 * tx + 1) * PITCH + n] = mk2(fabsf(fw.z), fabsf(fw.w));
        }
        __syncthreads();

        // Prefetch next chunk (overlaps with compute below).
        if (chunk + 1 < K / KB) {
            const float* xn = xbase + (chunk + 1) * KB;
            const float* wn = wbase + (chunk + 1) * KB;
#pragma unroll
            for (int i = 0; i < 4; ++i) {
                xr[i] = *(const v4f*)(xn + (16 * i) * K);
                wr[i] = *(const v4f*)(wn + (16 * i) * K);
            }
        }

#pragma unroll
        for (int kk = 0; kk < KKP; ++kk) {
            const v2f* xrow = &xs[kk * PITCH + 4 * ty];
            const v2f* wrow = &ws[kk * PITCH + 4 * tx];
            v4f xa = *(const v4f*)xrow;        // n = 4ty, 4ty+1 (k-pair each)
            v4f xb = *(const v4f*)(xrow + 2);  // n = 4ty+2, 4ty+3
            v4f wa = *(const v4f*)wrow;
            v4f wb = *(const v4f*)(wrow + 2);

            v2f xp[4] = { mk2(xa.x, xa.y), mk2(xa.z, xa.w),
                          mk2(xb.x, xb.y), mk2(xb.z, xb.w) };
            v2f wp[4] = { mk2(wa.x, wa.y), mk2(wa.z, wa.w),
                          mk2(wb.x, wb.y), mk2(wb.z, wb.w) };
#pragma unroll
            for (int i = 0; i < 4; ++i)
#pragma unroll
                for (int j = 0; j < 4; ++j) {
                    v2f s = xp[i] + wp[j];                      // v_pk_add_f32
                    acc[i][j] = fmaxf(acc[i][j], fmaxf(s.x, s.y)); // v_max3_f32
                }
        }
    }

#pragma unroll
    for (int i = 0; i < 4; ++i) {
        v4f o; o.x = acc[i][0]; o.y = acc[i][1]; o.z = acc[i][2]; o.w = acc[i][3];
        *(v4f*)(outg + (bn + 4 * ty + i) * M + bm + 4 * tx) = o;
    }
}

extern "C" void kernel_launch(void* const* d_in, const int* in_sizes, int n_in,
                              void* d_out, int out_size, void* d_ws, size_t ws_size,
                              hipStream_t stream)
{
    const float* x = (const float*)d_in[0];   // [1024, 256]
    const float* w = (const float*)d_in[1];   // [1024, 256]
    float* out = (float*)d_out;               // [1024, 1024]

    dim3 grid(256);   // 16 x 16 tiles of 64x64
    dim3 block(256);
    tropical_kernel<<<grid, block, 0, stream>>>(x, w, out);
}

// Round 2
// 70.860 us; speedup vs baseline: 1.0556x; 1.0556x over previous
//
#include <hip/hip_runtime.h>

// Tropical (max-plus) matmul: out[n,m] = max_k(|x[n,k]| + |w[m,k]|)
// N=1024, K=256, M=1024, fp32 in/out.
//
// Round 2: occupancy fix. R1 had 256 blocks x 4 waves = 1024 waves = exactly
// 1 wave/SIMD on MI355X (1024 SIMDs) -> all LDS/global latency fully exposed.
// Now: 32x32 tiles -> 1024 blocks x 4 waves = 4096 waves = 4 waves/SIMD,
// same total VALU work (2 insts per k-pair per output via v_pk_add_f32 +
// v_max3_f32), 2x2 outputs per thread, K chunked at 64 with register
// prefetch of the next chunk.

typedef float v2f __attribute__((ext_vector_type(2)));
typedef float v4f __attribute__((ext_vector_type(4)));

constexpr int TILE  = 32;        // output tile edge
constexpr int KB    = 64;        // k per chunk
constexpr int KKP   = KB / 2;    // 32 k-pairs per chunk
constexpr int PITCH = TILE + 2;  // v2f units: 34 -> 272 B row, 16B-aligned

__global__ void __launch_bounds__(256)
tropical_kernel(const float* __restrict__ xg, const float* __restrict__ wg,
                float* __restrict__ outg)
{
    constexpr int K = 256;
    constexpr int M = 1024;

    __shared__ __align__(16) v2f xs[KKP * PITCH];
    __shared__ __align__(16) v2f ws[KKP * PITCH];

    const int tid = threadIdx.x;
    const int tx = tid & 15;          // m-side (2 cols per thread)
    const int ty = tid >> 4;          // n-side (2 rows per thread), 0..15
    const int bn = (int)(blockIdx.x >> 5) * TILE;
    const int bm = (int)(blockIdx.x & 31) * TILE;

    // Staging coords: thread loads row r, 8 consecutive k at col c, per side.
    const int r = tid >> 3;           // 0..31
    const int c = (tid & 7) * 8;      // 0..56
    const float* xbase = xg + (bn + r) * K + c;
    const float* wbase = wg + (bm + r) * K + c;

    // Prefetch chunk 0.
    v4f xr0 = *(const v4f*)(xbase);
    v4f xr1 = *(const v4f*)(xbase + 4);
    v4f wr0 = *(const v4f*)(wbase);
    v4f wr1 = *(const v4f*)(wbase + 4);

    // Sums are >= 0, so 0 is a safe max-identity.
    float a00 = 0.f, a01 = 0.f, a10 = 0.f, a11 = 0.f;

    const int kp = c >> 1;            // first k-pair row this thread fills

    for (int chunk = 0; chunk < K / KB; ++chunk) {
        __syncthreads();              // previous chunk's LDS reads done
        xs[(kp + 0) * PITCH + r] = (v2f){fabsf(xr0.x), fabsf(xr0.y)};
        xs[(kp + 1) * PITCH + r] = (v2f){fabsf(xr0.z), fabsf(xr0.w)};
        xs[(kp + 2) * PITCH + r] = (v2f){fabsf(xr1.x), fabsf(xr1.y)};
        xs[(kp + 3) * PITCH + r] = (v2f){fabsf(xr1.z), fabsf(xr1.w)};
        ws[(kp + 0) * PITCH + r] = (v2f){fabsf(wr0.x), fabsf(wr0.y)};
        ws[(kp + 1) * PITCH + r] = (v2f){fabsf(wr0.z), fabsf(wr0.w)};
        ws[(kp + 2) * PITCH + r] = (v2f){fabsf(wr1.x), fabsf(wr1.y)};
        ws[(kp + 3) * PITCH + r] = (v2f){fabsf(wr1.z), fabsf(wr1.w)};
        __syncthreads();

        // Prefetch next chunk (overlaps with compute).
        if (chunk + 1 < K / KB) {
            const float* xn = xbase + (chunk + 1) * KB;
            const float* wn = wbase + (chunk + 1) * KB;
            xr0 = *(const v4f*)(xn);
            xr1 = *(const v4f*)(xn + 4);
            wr0 = *(const v4f*)(wn);
            wr1 = *(const v4f*)(wn + 4);
        }

#pragma unroll
        for (int kk = 0; kk < KKP; ++kk) {
            v4f xv = *(const v4f*)&xs[kk * PITCH + 2 * ty];  // n0,n1 k-pairs
            v4f wv = *(const v4f*)&ws[kk * PITCH + 2 * tx];  // m0,m1 k-pairs
            v2f x0 = {xv.x, xv.y}, x1 = {xv.z, xv.w};
            v2f w0 = {wv.x, wv.y}, w1 = {wv.z, wv.w};
            v2f s;
            s = x0 + w0; a00 = fmaxf(a00, fmaxf(s.x, s.y));  // pk_add + max3
            s = x0 + w1; a01 = fmaxf(a01, fmaxf(s.x, s.y));
            s = x1 + w0; a10 = fmaxf(a10, fmaxf(s.x, s.y));
            s = x1 + w1; a11 = fmaxf(a11, fmaxf(s.x, s.y));
        }
    }

    const int n0 = bn + 2 * ty;
    const int m0 = bm + 2 * tx;
    *(v2f*)(outg + n0 * M + m0)       = (v2f){a00, a01};
    *(v2f*)(outg + (n0 + 1) * M + m0) = (v2f){a10, a11};
}

extern "C" void kernel_launch(void* const* d_in, const int* in_sizes, int n_in,
                              void* d_out, int out_size, void* d_ws, size_t ws_size,
                              hipStream_t stream)
{
    const float* x = (const float*)d_in[0];   // [1024, 256]
    const float* w = (const float*)d_in[1];   // [1024, 256]
    float* out = (float*)d_out;               // [1024, 1024]

    dim3 grid(1024);   // 32 x 32 tiles of 32x32
    dim3 block(256);
    tropical_kernel<<<grid, block, 0, stream>>>(x, w, out);
}